// Round 1
// baseline (2401.734 us; speedup 1.0000x reference)
//
#include <hip/hip_runtime.h>
#include <math.h>

#define TPB 256
static inline int cdiv(int a, int b) { return (a + b - 1) / b; }

// ---------------- conv1: x NHWC (287,287,3) -> (96,139,139), 11x11 s2 ----------------
__global__ void conv1_k(const float* __restrict__ x, const float* __restrict__ w,
                        const float* __restrict__ b, float* __restrict__ out) {
    const int HW = 139 * 139;
    int idx = blockIdx.x * blockDim.x + threadIdx.x;
    if (idx >= 96 * HW) return;
    int o = idx / HW, p = idx % HW;
    int oy = p / 139, ox = p % 139;
    int iy = oy * 2, ix = ox * 2;
    float acc = b[o];
    const float* wo = w + o * 3 * 121;
    for (int c = 0; c < 3; ++c) {
        const float* wcp = wo + c * 121;
        for (int ki = 0; ki < 11; ++ki) {
            const float* xr = x + ((iy + ki) * 287 + ix) * 3 + c;
            const float* wrp = wcp + ki * 11;
#pragma unroll 11
            for (int kj = 0; kj < 11; ++kj)
                acc = fmaf(xr[kj * 3], wrp[kj], acc);
        }
    }
    out[idx] = acc;
}

// ---------------- maxpool 3x3 s2 + relu ----------------
__global__ void pool_relu_k(const float* __restrict__ in, float* __restrict__ out,
                            int C, int Hin) {
    int Ho = (Hin - 3) / 2 + 1;
    int total = C * Ho * Ho;
    int idx = blockIdx.x * blockDim.x + threadIdx.x;
    if (idx >= total) return;
    int c = idx / (Ho * Ho), p = idx % (Ho * Ho);
    int oy = p / Ho, ox = p % Ho;
    const float* ip = in + (c * Hin + oy * 2) * Hin + ox * 2;
    float m = -INFINITY;
#pragma unroll
    for (int ki = 0; ki < 3; ++ki)
#pragma unroll
        for (int kj = 0; kj < 3; ++kj)
            m = fmaxf(m, ip[ki * Hin + kj]);
    out[idx] = fmaxf(m, 0.f);
}

// ---------------- conv2: (96,69,69) -> (256,65,65), 5x5 s1 ----------------
__global__ void conv2_k(const float* __restrict__ in, const float* __restrict__ w,
                        const float* __restrict__ b, float* __restrict__ out) {
    const int Ho = 65, Hin = 69;
    int idx = blockIdx.x * blockDim.x + threadIdx.x;
    if (idx >= 256 * Ho * Ho) return;
    int o = idx / (Ho * Ho), p = idx % (Ho * Ho);
    int oy = p / Ho, ox = p % Ho;
    float acc = b[o];
    const float* wo = w + o * 96 * 25;
    for (int c = 0; c < 96; ++c) {
        const float* ip = in + (c * Hin + oy) * Hin + ox;
        const float* wp = wo + c * 25;
#pragma unroll
        for (int ki = 0; ki < 5; ++ki)
#pragma unroll
            for (int kj = 0; kj < 5; ++kj)
                acc = fmaf(ip[ki * Hin + kj], wp[ki * 5 + kj], acc);
    }
    out[idx] = acc;
}

// ---------------- generic 3x3 s1 conv, optional relu ----------------
__global__ void conv3x3_k(const float* __restrict__ in, const float* __restrict__ w,
                          const float* __restrict__ b, float* __restrict__ out,
                          int Cin, int Cout, int Hin, int relu) {
    int Ho = Hin - 2;
    int total = Cout * Ho * Ho;
    int idx = blockIdx.x * blockDim.x + threadIdx.x;
    if (idx >= total) return;
    int o = idx / (Ho * Ho), p = idx % (Ho * Ho);
    int oy = p / Ho, ox = p % Ho;
    float acc = b[o];
    const float* wo = w + o * Cin * 9;
    for (int c = 0; c < Cin; ++c) {
        const float* ip = in + (c * Hin + oy) * Hin + ox;
        const float* wp = wo + c * 9;
#pragma unroll
        for (int ki = 0; ki < 3; ++ki) {
            acc = fmaf(ip[ki * Hin + 0], wp[ki * 3 + 0], acc);
            acc = fmaf(ip[ki * Hin + 1], wp[ki * 3 + 1], acc);
            acc = fmaf(ip[ki * Hin + 2], wp[ki * 3 + 2], acc);
        }
    }
    out[idx] = relu ? fmaxf(acc, 0.f) : acc;
}

// ---------------- depthwise 4x4 correlation ----------------
// in: (256,24,24), z: (8,256,16), out: (8,256,441)  [441 = 21*21]
__global__ void dwcorr_k(const float* __restrict__ in, const float* __restrict__ z,
                         float* __restrict__ out) {
    const int L = 441;
    int idx = blockIdx.x * blockDim.x + threadIdx.x;
    if (idx >= 8 * 256 * L) return;
    int m = idx / (256 * L);
    int r = idx % (256 * L);
    int c = r / L, l = r % L;
    int y = l / 21, x = l % 21;
    const float* ip = in + (c * 24 + y) * 24 + x;
    const float* zp = z + (m * 256 + c) * 16;
    float acc = 0.f;
#pragma unroll
    for (int ki = 0; ki < 4; ++ki)
#pragma unroll
        for (int kj = 0; kj < 4; ++kj)
            acc = fmaf(ip[ki * 24 + kj], zp[ki * 4 + kj], acc);
    out[idx] = acc;
}

// ---------------- 1x1 conv over (M, Cin, L) -> (M, Cout, L) ----------------
__global__ void conv1x1_k(const float* __restrict__ in, const float* __restrict__ w,
                          const float* __restrict__ b, float* __restrict__ out,
                          int M, int Cin, int Cout, int L, int relu) {
    int total = M * Cout * L;
    int idx = blockIdx.x * blockDim.x + threadIdx.x;
    if (idx >= total) return;
    int m = idx / (Cout * L);
    int r = idx % (Cout * L);
    int o = r / L, l = r % L;
    float acc = b[o];
    const float* ip = in + (m * Cin) * L + l;
    const float* wp = w + o * Cin;
    for (int c = 0; c < Cin; ++c)
        acc = fmaf(ip[c * L], wp[c], acc);
    out[idx] = relu ? fmaxf(acc, 0.f) : acc;
}

// ---------------- epilogue: softmax pair + anchor decode ----------------
// cls: (8,10,441), reg: (8,20,441), anc*: (8,2205), out: 5 x (8,2205)
__global__ void epilogue_k(const float* __restrict__ cls, const float* __restrict__ reg,
                           const float* __restrict__ a0, const float* __restrict__ a1,
                           const float* __restrict__ a2, const float* __restrict__ a3,
                           float* __restrict__ out) {
    const int N = 8 * 2205;
    int idx = blockIdx.x * blockDim.x + threadIdx.x;
    if (idx >= N) return;
    int m = idx / 2205, j = idx % 2205;
    int a = j / 441, pos = j % 441;
    const float* cm = cls + m * 10 * 441;
    const float* rm = reg + m * 20 * 441;
    float c0 = cm[a * 441 + pos];
    float c1 = cm[(5 + a) * 441 + pos];
    float s1 = 1.f / (1.f + expf(c0 - c1));
    float dl0 = rm[a * 441 + pos];
    float dl1 = rm[(5 + a) * 441 + pos];
    float dl2 = rm[(10 + a) * 441 + pos];
    float dl3 = rm[(15 + a) * 441 + pos];
    float A2 = a2[idx], A3 = a3[idx];
    out[0 * N + idx] = fmaf(dl0, A2, a0[idx]);
    out[1 * N + idx] = fmaf(dl1, A3, a1[idx]);
    out[2 * N + idx] = expf(dl2) * A2;
    out[3 * N + idx] = expf(dl3) * A3;
    out[4 * N + idx] = s1;
}

extern "C" void kernel_launch(void* const* d_in, const int* in_sizes, int n_in,
                              void* d_out, int out_size, void* d_ws, size_t ws_size,
                              hipStream_t stream) {
    const float* x     = (const float*)d_in[0];
    const float* z_reg = (const float*)d_in[1];
    const float* z_cls = (const float*)d_in[2];
    const float* bb_w1 = (const float*)d_in[3];
    const float* bb_b1 = (const float*)d_in[4];
    const float* bb_w2 = (const float*)d_in[5];
    const float* bb_b2 = (const float*)d_in[6];
    const float* bb_w3 = (const float*)d_in[7];
    const float* bb_b3 = (const float*)d_in[8];
    const float* bb_w4 = (const float*)d_in[9];
    const float* bb_b4 = (const float*)d_in[10];
    const float* bb_w5 = (const float*)d_in[11];
    const float* bb_b5 = (const float*)d_in[12];
    const float* wr    = (const float*)d_in[13];
    const float* br    = (const float*)d_in[14];
    const float* wc    = (const float*)d_in[15];
    const float* bc    = (const float*)d_in[16];
    const float* rh_w1 = (const float*)d_in[17];
    const float* rh_b1 = (const float*)d_in[18];
    const float* rh_w2 = (const float*)d_in[19];
    const float* rh_b2 = (const float*)d_in[20];
    const float* ch_w1 = (const float*)d_in[21];
    const float* ch_b1 = (const float*)d_in[22];
    const float* ch_w2 = (const float*)d_in[23];
    const float* ch_b2 = (const float*)d_in[24];
    const float* anc0  = (const float*)d_in[25];
    const float* anc1  = (const float*)d_in[26];
    const float* anc2  = (const float*)d_in[27];
    const float* anc3  = (const float*)d_in[28];

    float* ws = (float*)d_ws;
    float* bufA     = ws;                     // 1,854,816 floats (conv1/conv2/conv3/xf ping)
    float* bufB     = bufA + 1854816;         //   457,056 floats (pools/conv4/c_x,r_x pong)
    float* cls_corr = bufB + 457056;          //   903,168
    float* reg_corr = cls_corr + 903168;      //   903,168
    float* hid      = reg_corr + 903168;      //   903,168 (reused cls then reg)
    float* cls_out  = hid + 903168;           //    35,280
    float* reg_out  = cls_out + 35280;        //    70,560

    float* c_x = bufB;                        // (256,24,24)
    float* r_x = bufB + 147456;               // (256,24,24)

    // backbone
    conv1_k<<<cdiv(96 * 139 * 139, TPB), TPB, 0, stream>>>(x, bb_w1, bb_b1, bufA);
    pool_relu_k<<<cdiv(96 * 69 * 69, TPB), TPB, 0, stream>>>(bufA, bufB, 96, 139);
    conv2_k<<<cdiv(256 * 65 * 65, TPB), TPB, 0, stream>>>(bufB, bb_w2, bb_b2, bufA);
    pool_relu_k<<<cdiv(256 * 32 * 32, TPB), TPB, 0, stream>>>(bufA, bufB, 256, 65);
    conv3x3_k<<<cdiv(384 * 30 * 30, TPB), TPB, 0, stream>>>(bufB, bb_w3, bb_b3, bufA, 256, 384, 32, 1);
    conv3x3_k<<<cdiv(384 * 28 * 28, TPB), TPB, 0, stream>>>(bufA, bb_w4, bb_b4, bufB, 384, 384, 30, 1);
    conv3x3_k<<<cdiv(256 * 26 * 26, TPB), TPB, 0, stream>>>(bufB, bb_w5, bb_b5, bufA, 384, 256, 28, 0);

    // search-region convs: c_x uses (wr,br), r_x uses (wc,bc) -- reference naming
    conv3x3_k<<<cdiv(256 * 24 * 24, TPB), TPB, 0, stream>>>(bufA, wr, br, c_x, 256, 256, 26, 1);
    conv3x3_k<<<cdiv(256 * 24 * 24, TPB), TPB, 0, stream>>>(bufA, wc, bc, r_x, 256, 256, 26, 1);

    // depthwise correlation: c_x (x) z_cls -> cls_corr ; r_x (x) z_reg -> reg_corr
    dwcorr_k<<<cdiv(8 * 256 * 441, TPB), TPB, 0, stream>>>(c_x, z_cls, cls_corr);
    dwcorr_k<<<cdiv(8 * 256 * 441, TPB), TPB, 0, stream>>>(r_x, z_reg, reg_corr);

    // cls head: 256 -> 256 (relu) -> 10
    conv1x1_k<<<cdiv(8 * 256 * 441, TPB), TPB, 0, stream>>>(cls_corr, ch_w1, ch_b1, hid, 8, 256, 256, 441, 1);
    conv1x1_k<<<cdiv(8 * 10 * 441, TPB), TPB, 0, stream>>>(hid, ch_w2, ch_b2, cls_out, 8, 256, 10, 441, 0);

    // reg head: 256 -> 256 (relu) -> 20
    conv1x1_k<<<cdiv(8 * 256 * 441, TPB), TPB, 0, stream>>>(reg_corr, rh_w1, rh_b1, hid, 8, 256, 256, 441, 1);
    conv1x1_k<<<cdiv(8 * 20 * 441, TPB), TPB, 0, stream>>>(hid, rh_w2, rh_b2, reg_out, 8, 256, 20, 441, 0);

    // decode
    epilogue_k<<<cdiv(8 * 2205, TPB), TPB, 0, stream>>>(cls_out, reg_out, anc0, anc1, anc2, anc3,
                                                        (float*)d_out);
}

// Round 2
// 1419.177 us; speedup vs baseline: 1.6923x; 1.6923x over previous
//
#include <hip/hip_runtime.h>
#include <math.h>

#define TPB 256
static inline int cdiv(int a, int b) { return (a + b - 1) / b; }

// ================= conv1: x NHWC (287,287,3) -> (96,139,139), 11x11 s2 =================
// Block: one output channel, 32x32 output tile; thread 2x2 outputs. Input channel staged in LDS.
__global__ __launch_bounds__(256) void conv1_tile_k(const float* __restrict__ x,
                                                    const float* __restrict__ w,
                                                    const float* __restrict__ b,
                                                    float* __restrict__ out) {
    __shared__ float s_in[73 * 74];   // one channel, 73 rows x stride 74
    __shared__ float s_w[363];
    int bid = blockIdx.x;
    int o = bid / 25;
    int r = bid % 25;
    int y0 = (r / 5) * 32, x0 = (r % 5) * 32;   // output tile origin
    int iy0 = y0 * 2, ix0 = x0 * 2;             // input origin
    int t = threadIdx.x;
    int sy = t >> 4, sx = t & 15;               // 16x16 thread grid, 2x2 outputs each
    for (int i = t; i < 363; i += 256) s_w[i] = w[o * 363 + i];
    float bv = b[o];
    float acc00 = bv, acc01 = bv, acc10 = bv, acc11 = bv;
    for (int c = 0; c < 3; ++c) {
        __syncthreads();
        for (int i = t; i < 73 * 73; i += 256) {
            int ry = i / 73, rx = i % 73;
            int gy = iy0 + ry, gx = ix0 + rx;
            s_in[ry * 74 + rx] = (gy < 287 && gx < 287) ? x[((size_t)gy * 287 + gx) * 3 + c] : 0.f;
        }
        __syncthreads();
        const float* wc = &s_w[c * 121];
#pragma unroll
        for (int ki = 0; ki < 11; ++ki) {
            float wr[11];
#pragma unroll
            for (int kj = 0; kj < 11; ++kj) wr[kj] = wc[ki * 11 + kj];
            const float* r0 = &s_in[(4 * sy + ki) * 74 + 4 * sx];
            const float* r1 = r0 + 148;  // +2 rows
            float a0[13], a1[13];
#pragma unroll
            for (int cc = 0; cc < 12; cc += 2) {
                float2 v0 = *(const float2*)&r0[cc]; a0[cc] = v0.x; a0[cc + 1] = v0.y;
                float2 v1 = *(const float2*)&r1[cc]; a1[cc] = v1.x; a1[cc + 1] = v1.y;
            }
            a0[12] = r0[12]; a1[12] = r1[12];
#pragma unroll
            for (int kj = 0; kj < 11; ++kj) {
                float wv = wr[kj];
                acc00 = fmaf(a0[kj], wv, acc00);
                acc01 = fmaf(a0[kj + 2], wv, acc01);
                acc10 = fmaf(a1[kj], wv, acc10);
                acc11 = fmaf(a1[kj + 2], wv, acc11);
            }
        }
    }
    int oy = y0 + 2 * sy, ox = x0 + 2 * sx;
    size_t ob = (size_t)o * 139 * 139;
    if (oy < 139) {
        if (ox < 139)     out[ob + (size_t)oy * 139 + ox] = acc00;
        if (ox + 1 < 139) out[ob + (size_t)oy * 139 + ox + 1] = acc01;
    }
    if (oy + 1 < 139) {
        if (ox < 139)     out[ob + (size_t)(oy + 1) * 139 + ox] = acc10;
        if (ox + 1 < 139) out[ob + (size_t)(oy + 1) * 139 + ox + 1] = acc11;
    }
}

// ================= maxpool 3x3 s2 + relu =================
__global__ void pool_relu_k(const float* __restrict__ in, float* __restrict__ out,
                            int C, int Hin) {
    int Ho = (Hin - 3) / 2 + 1;
    int total = C * Ho * Ho;
    int idx = blockIdx.x * blockDim.x + threadIdx.x;
    if (idx >= total) return;
    int c = idx / (Ho * Ho), p = idx % (Ho * Ho);
    int oy = p / Ho, ox = p % Ho;
    const float* ip = in + ((size_t)c * Hin + oy * 2) * Hin + ox * 2;
    float m = -INFINITY;
#pragma unroll
    for (int ki = 0; ki < 3; ++ki)
#pragma unroll
        for (int kj = 0; kj < 3; ++kj)
            m = fmaxf(m, ip[ki * Hin + kj]);
    out[idx] = fmaxf(m, 0.f);
}

// ================= tiled KxK s1 conv: 16 out-ch x 8x8 spatial per block =================
// thread: 1 output channel x 2x2 spatial. Input tile + weight slice staged in LDS, CBLK ch/step.
template <int K, int CBLK>
__global__ __launch_bounds__(256) void conv_tile_k(const float* __restrict__ in,
                                                   const float* __restrict__ w,
                                                   const float* __restrict__ b,
                                                   float* __restrict__ out,
                                                   int Cin, int Hin, int Ho, int nt, int relu) {
    constexpr int K2 = K * K;
    constexpr int IN_W = 8 + K - 1;
    constexpr int IN_T2 = IN_W * IN_W;
    __shared__ float s_in[CBLK * IN_T2];
    __shared__ float s_w[CBLK * 16 * K2];
    int bid = blockIdx.x;
    int ot = bid / (nt * nt);
    int r = bid % (nt * nt);
    int y0 = (r / nt) * 8, x0 = (r % nt) * 8;
    int o0 = ot * 16;
    int t = threadIdx.x;
    int o_local = t >> 4;
    int sp = t & 15;
    int sy = sp >> 2, sx = sp & 3;
    int o = o0 + o_local;
    float bv = b[o];
    float acc00 = bv, acc01 = bv, acc10 = bv, acc11 = bv;

    for (int c0 = 0; c0 < Cin; c0 += CBLK) {
        // stage input tile (zero-padded at borders)
        for (int i = t; i < CBLK * IN_T2; i += 256) {
            int ci = i / IN_T2, rr = i % IN_T2;
            int ry = rr / IN_W, rx = rr % IN_W;
            int gy = y0 + ry, gx = x0 + rx;
            float v = 0.f;
            if (gy < Hin && gx < Hin)
                v = in[(size_t)(c0 + ci) * Hin * Hin + (size_t)gy * Hin + gx];
            s_in[i] = v;
        }
        // stage weights (per ol: CBLK*K2 contiguous floats from global)
        for (int i = t; i < 16 * CBLK * K2; i += 256) {
            int ol = i / (CBLK * K2), j = i % (CBLK * K2);
            int ci = j / K2, kk = j % K2;
            s_w[ci * 16 * K2 + ol * K2 + kk] =
                w[(size_t)(o0 + ol) * Cin * K2 + (size_t)(c0 + ci) * K2 + kk];
        }
        __syncthreads();
#pragma unroll
        for (int ci = 0; ci < CBLK; ++ci) {
            float wreg[K2];
            const float* wp = &s_w[ci * 16 * K2 + o_local * K2];
#pragma unroll
            for (int k = 0; k < K2; ++k) wreg[k] = wp[k];
            float xr[K + 1][K + 1];
            const float* ip = &s_in[ci * IN_T2 + (2 * sy) * IN_W + 2 * sx];
#pragma unroll
            for (int rr = 0; rr < K + 1; ++rr)
#pragma unroll
                for (int cc = 0; cc < K + 1; cc += 2) {
                    float2 v = *(const float2*)&ip[rr * IN_W + cc];
                    xr[rr][cc] = v.x; xr[rr][cc + 1] = v.y;
                }
#pragma unroll
            for (int ki = 0; ki < K; ++ki)
#pragma unroll
                for (int kj = 0; kj < K; ++kj) {
                    float wv = wreg[ki * K + kj];
                    acc00 = fmaf(xr[ki][kj],         wv, acc00);
                    acc01 = fmaf(xr[ki][kj + 1],     wv, acc01);
                    acc10 = fmaf(xr[ki + 1][kj],     wv, acc10);
                    acc11 = fmaf(xr[ki + 1][kj + 1], wv, acc11);
                }
        }
        __syncthreads();
    }
    if (relu) {
        acc00 = fmaxf(acc00, 0.f); acc01 = fmaxf(acc01, 0.f);
        acc10 = fmaxf(acc10, 0.f); acc11 = fmaxf(acc11, 0.f);
    }
    int yy = y0 + 2 * sy, xx = x0 + 2 * sx;
    size_t ob = (size_t)o * Ho * Ho;
    if (yy < Ho) {
        if (xx < Ho)     out[ob + (size_t)yy * Ho + xx] = acc00;
        if (xx + 1 < Ho) out[ob + (size_t)yy * Ho + xx + 1] = acc01;
    }
    if (yy + 1 < Ho) {
        if (xx < Ho)     out[ob + (size_t)(yy + 1) * Ho + xx] = acc10;
        if (xx + 1 < Ho) out[ob + (size_t)(yy + 1) * Ho + xx + 1] = acc11;
    }
}

// ================= depthwise 4x4 correlation =================
__global__ void dwcorr_k(const float* __restrict__ in, const float* __restrict__ z,
                         float* __restrict__ out) {
    const int L = 441;
    int idx = blockIdx.x * blockDim.x + threadIdx.x;
    if (idx >= 8 * 256 * L) return;
    int m = idx / (256 * L);
    int r = idx % (256 * L);
    int c = r / L, l = r % L;
    int y = l / 21, x = l % 21;
    const float* ip = in + ((size_t)c * 24 + y) * 24 + x;
    const float* zp = z + ((size_t)m * 256 + c) * 16;
    float acc = 0.f;
#pragma unroll
    for (int ki = 0; ki < 4; ++ki)
#pragma unroll
        for (int kj = 0; kj < 4; ++kj)
            acc = fmaf(ip[ki * 24 + kj], zp[ki * 4 + kj], acc);
    out[idx] = acc;
}

// ================= tiled 1x1 conv (256->256 + relu), batched over m =================
// tile: 64 o x 64 l; thread 4x4. grid = 8m x 4 x 7
__global__ __launch_bounds__(256) void conv1x1_tile_k(const float* __restrict__ in,
                                                      const float* __restrict__ w,
                                                      const float* __restrict__ b,
                                                      float* __restrict__ out) {
    __shared__ float s_x[16 * 64];
    __shared__ float s_w[16 * 64];
    int bid = blockIdx.x;
    int m = bid / 28;
    int r = bid % 28;
    int o0 = (r / 7) * 64, l0 = (r % 7) * 64;
    int t = threadIdx.x;
    int lg = t & 15, og = t >> 4;
    int ll = lg * 4, ol = og * 4;
    float acc[4][4] = {};
    for (int c0 = 0; c0 < 256; c0 += 16) {
#pragma unroll
        for (int k = 0; k < 4; ++k) {
            int idx = t + k * 256;
            int c = idx >> 6, l = idx & 63;
            int gl = l0 + l;
            s_x[c * 64 + l] = (gl < 441) ? in[((size_t)m * 256 + c0 + c) * 441 + gl] : 0.f;
            int oo = idx >> 4, cc = idx & 15;
            s_w[cc * 64 + oo] = w[(size_t)(o0 + oo) * 256 + c0 + cc];
        }
        __syncthreads();
#pragma unroll
        for (int c = 0; c < 16; ++c) {
            float4 xv = *(const float4*)&s_x[c * 64 + ll];
            float4 wv = *(const float4*)&s_w[c * 64 + ol];
            float xa[4] = {xv.x, xv.y, xv.z, xv.w};
            float wa[4] = {wv.x, wv.y, wv.z, wv.w};
#pragma unroll
            for (int i = 0; i < 4; ++i)
#pragma unroll
                for (int j = 0; j < 4; ++j)
                    acc[i][j] = fmaf(wa[i], xa[j], acc[i][j]);
        }
        __syncthreads();
    }
#pragma unroll
    for (int i = 0; i < 4; ++i) {
        int o = o0 + ol + i;
        float bv = b[o];
#pragma unroll
        for (int j = 0; j < 4; ++j) {
            int gl = l0 + ll + j;
            if (gl < 441)
                out[((size_t)m * 256 + o) * 441 + gl] = fmaxf(acc[i][j] + bv, 0.f);
        }
    }
}

// ================= naive 1x1 conv (small Cout heads) =================
__global__ void conv1x1_k(const float* __restrict__ in, const float* __restrict__ w,
                          const float* __restrict__ b, float* __restrict__ out,
                          int M, int Cin, int Cout, int L, int relu) {
    int total = M * Cout * L;
    int idx = blockIdx.x * blockDim.x + threadIdx.x;
    if (idx >= total) return;
    int m = idx / (Cout * L);
    int r = idx % (Cout * L);
    int o = r / L, l = r % L;
    float acc = b[o];
    const float* ip = in + ((size_t)m * Cin) * L + l;
    const float* wp = w + (size_t)o * Cin;
    for (int c = 0; c < Cin; ++c)
        acc = fmaf(ip[(size_t)c * L], wp[c], acc);
    out[idx] = relu ? fmaxf(acc, 0.f) : acc;
}

// ================= epilogue: softmax pair + anchor decode =================
__global__ void epilogue_k(const float* __restrict__ cls, const float* __restrict__ reg,
                           const float* __restrict__ a0, const float* __restrict__ a1,
                           const float* __restrict__ a2, const float* __restrict__ a3,
                           float* __restrict__ out) {
    const int N = 8 * 2205;
    int idx = blockIdx.x * blockDim.x + threadIdx.x;
    if (idx >= N) return;
    int m = idx / 2205, j = idx % 2205;
    int a = j / 441, pos = j % 441;
    const float* cm = cls + (size_t)m * 10 * 441;
    const float* rm = reg + (size_t)m * 20 * 441;
    float c0 = cm[a * 441 + pos];
    float c1 = cm[(5 + a) * 441 + pos];
    float s1 = 1.f / (1.f + expf(c0 - c1));
    float dl0 = rm[a * 441 + pos];
    float dl1 = rm[(5 + a) * 441 + pos];
    float dl2 = rm[(10 + a) * 441 + pos];
    float dl3 = rm[(15 + a) * 441 + pos];
    float A2 = a2[idx], A3 = a3[idx];
    out[0 * N + idx] = fmaf(dl0, A2, a0[idx]);
    out[1 * N + idx] = fmaf(dl1, A3, a1[idx]);
    out[2 * N + idx] = expf(dl2) * A2;
    out[3 * N + idx] = expf(dl3) * A3;
    out[4 * N + idx] = s1;
}

extern "C" void kernel_launch(void* const* d_in, const int* in_sizes, int n_in,
                              void* d_out, int out_size, void* d_ws, size_t ws_size,
                              hipStream_t stream) {
    const float* x     = (const float*)d_in[0];
    const float* z_reg = (const float*)d_in[1];
    const float* z_cls = (const float*)d_in[2];
    const float* bb_w1 = (const float*)d_in[3];
    const float* bb_b1 = (const float*)d_in[4];
    const float* bb_w2 = (const float*)d_in[5];
    const float* bb_b2 = (const float*)d_in[6];
    const float* bb_w3 = (const float*)d_in[7];
    const float* bb_b3 = (const float*)d_in[8];
    const float* bb_w4 = (const float*)d_in[9];
    const float* bb_b4 = (const float*)d_in[10];
    const float* bb_w5 = (const float*)d_in[11];
    const float* bb_b5 = (const float*)d_in[12];
    const float* wr    = (const float*)d_in[13];
    const float* br    = (const float*)d_in[14];
    const float* wc    = (const float*)d_in[15];
    const float* bc    = (const float*)d_in[16];
    const float* rh_w1 = (const float*)d_in[17];
    const float* rh_b1 = (const float*)d_in[18];
    const float* rh_w2 = (const float*)d_in[19];
    const float* rh_b2 = (const float*)d_in[20];
    const float* ch_w1 = (const float*)d_in[21];
    const float* ch_b1 = (const float*)d_in[22];
    const float* ch_w2 = (const float*)d_in[23];
    const float* ch_b2 = (const float*)d_in[24];
    const float* anc0  = (const float*)d_in[25];
    const float* anc1  = (const float*)d_in[26];
    const float* anc2  = (const float*)d_in[27];
    const float* anc3  = (const float*)d_in[28];

    float* ws = (float*)d_ws;
    float* bufA     = ws;                     // 1,854,816 floats
    float* bufB     = bufA + 1854816;         //   457,056 floats
    float* cls_corr = bufB + 457056;          //   903,168
    float* reg_corr = cls_corr + 903168;      //   903,168
    float* hid      = reg_corr + 903168;      //   903,168
    float* cls_out  = hid + 903168;           //    35,280
    float* reg_out  = cls_out + 35280;        //    70,560

    float* c_x = bufB;                        // (256,24,24)
    float* r_x = bufB + 147456;               // (256,24,24)

    // backbone
    conv1_tile_k<<<96 * 25, 256, 0, stream>>>(x, bb_w1, bb_b1, bufA);
    pool_relu_k<<<cdiv(96 * 69 * 69, TPB), TPB, 0, stream>>>(bufA, bufB, 96, 139);
    conv_tile_k<5, 8><<<16 * 81, 256, 0, stream>>>(bufB, bb_w2, bb_b2, bufA, 96, 69, 65, 9, 0);
    pool_relu_k<<<cdiv(256 * 32 * 32, TPB), TPB, 0, stream>>>(bufA, bufB, 256, 65);
    conv_tile_k<3, 8><<<24 * 16, 256, 0, stream>>>(bufB, bb_w3, bb_b3, bufA, 256, 32, 30, 4, 1);
    conv_tile_k<3, 8><<<24 * 16, 256, 0, stream>>>(bufA, bb_w4, bb_b4, bufB, 384, 30, 28, 4, 1);
    conv_tile_k<3, 8><<<16 * 16, 256, 0, stream>>>(bufB, bb_w5, bb_b5, bufA, 384, 28, 26, 4, 0);

    // search-region convs: c_x uses (wr,br), r_x uses (wc,bc) -- reference naming
    conv_tile_k<3, 8><<<16 * 9, 256, 0, stream>>>(bufA, wr, br, c_x, 256, 26, 24, 3, 1);
    conv_tile_k<3, 8><<<16 * 9, 256, 0, stream>>>(bufA, wc, bc, r_x, 256, 26, 24, 3, 1);

    // depthwise correlation
    dwcorr_k<<<cdiv(8 * 256 * 441, TPB), TPB, 0, stream>>>(c_x, z_cls, cls_corr);
    dwcorr_k<<<cdiv(8 * 256 * 441, TPB), TPB, 0, stream>>>(r_x, z_reg, reg_corr);

    // cls head
    conv1x1_tile_k<<<8 * 28, 256, 0, stream>>>(cls_corr, ch_w1, ch_b1, hid);
    conv1x1_k<<<cdiv(8 * 10 * 441, TPB), TPB, 0, stream>>>(hid, ch_w2, ch_b2, cls_out, 8, 256, 10, 441, 0);

    // reg head
    conv1x1_tile_k<<<8 * 28, 256, 0, stream>>>(reg_corr, rh_w1, rh_b1, hid);
    conv1x1_k<<<cdiv(8 * 20 * 441, TPB), TPB, 0, stream>>>(hid, rh_w2, rh_b2, reg_out, 8, 256, 20, 441, 0);

    // decode
    epilogue_k<<<cdiv(8 * 2205, TPB), TPB, 0, stream>>>(cls_out, reg_out, anc0, anc1, anc2, anc3,
                                                        (float*)d_out);
}

// Round 3
// 361.890 us; speedup vs baseline: 6.6366x; 3.9216x over previous
//
#include <hip/hip_runtime.h>
#include <math.h>

#define TPB 256
static inline int cdiv(int a, int b) { return (a + b - 1) / b; }

typedef short bf8 __attribute__((ext_vector_type(8)));   // 8 bf16 (4 VGPRs)
typedef float f4 __attribute__((ext_vector_type(4)));    // mfma acc

__device__ inline float b2f(unsigned short u) {
    union { unsigned int i; float f; } v; v.i = ((unsigned int)u) << 16; return v.f;
}
__device__ inline short f2b(float f) {
    union { float f; unsigned int u; } v; v.f = f;
    unsigned int r = v.u + 0x7FFF + ((v.u >> 16) & 1);
    return (short)(r >> 16);
}

// ---------- weight convert: W[O][C][K2] f32 -> Wt[K2][Ot][C] bf16 (rows ooff..ooff+O-1) ----------
__global__ void wconv_k(const float* __restrict__ in, short* __restrict__ out,
                        int O, int C, int K2, int Ot, int ooff) {
    int idx = blockIdx.x * blockDim.x + threadIdx.x;
    if (idx >= O * C * K2) return;
    int c = idx % C;
    int o = (idx / C) % O;
    int kk = idx / (C * O);
    out[(size_t)kk * Ot * C + (size_t)(ooff + o) * C + c] =
        f2b(in[(size_t)o * C * K2 + (size_t)c * K2 + kk]);
}

// ---------- conv1 weights: W[96][3][11][11] -> Wt1[ki][96][64], k=kj*3+c, zero-pad k>=33 ----------
__global__ void wconv1_k(const float* __restrict__ in, short* __restrict__ out) {
    int idx = blockIdx.x * blockDim.x + threadIdx.x;
    if (idx >= 11 * 96 * 64) return;
    int k = idx % 64;
    int o = (idx / 64) % 96;
    int ki = idx / (64 * 96);
    float v = 0.f;
    if (k < 33) {
        int kj = k / 3, c = k % 3;
        v = in[o * 363 + c * 121 + ki * 11 + kj];
    }
    out[idx] = f2b(v);
}

// ---------- bias concat helper ----------
__global__ void copy_biases_k(const float* br, const float* bc, const float* chb1,
                              const float* rhb1, float* bcat, float* bcat2) {
    int t = blockIdx.x * blockDim.x + threadIdx.x;
    if (t < 256) bcat[t] = br[t];
    else if (t < 512) bcat[t] = bc[t - 256];
    else if (t < 768) bcat2[t - 512] = chb1[t - 512];
    else if (t < 1024) bcat2[t - 768 + 256] = rhb1[t - 768];
}

// ---------- generic implicit-GEMM conv (bf16 MFMA) ----------
// in:  NHWC bf16 [*, Cin];  wt: [K2][N][Cin] bf16;  out: [M][N] bf16
// block tile 64m x 64n, 4 waves 2x2 of 32x32 each.
__global__ __launch_bounds__(256) void gemm_conv_k(
        const short* __restrict__ in, const short* __restrict__ wt,
        const float* __restrict__ bias, short* __restrict__ out,
        int M, int N, int Cin, int Win, int Wo, int Kh, int Kw,
        int relu, int msplit, int wsec, int bsec, int nt) {
    __shared__ short sa[64 * 40];
    __shared__ short sb[64 * 40];
    int bid = blockIdx.x;
    int m0 = (bid / nt) * 64, n0 = (bid % nt) * 64;
    int t = threadIdx.x;
    int lane = t & 63;
    int w = t >> 6, wm = w >> 1, wn = w & 1;
    int sec = (m0 >= msplit) ? 1 : 0;
    const short* wts = wt + (size_t)sec * wsec;
    const float* bs = bias + sec * bsec;

    int mr = m0 + lane; if (mr > M - 1) mr = M - 1;
    int oy = mr / Wo, ox = mr - oy * Wo;
    size_t pixbase = ((size_t)oy * Win + ox) * Cin;
    int nr = n0 + lane; if (nr > N - 1) nr = N - 1;
    int kc = t >> 6;  // k-chunk 0..3 (8 bf16 each)

    f4 acc00 = {0.f, 0.f, 0.f, 0.f}, acc01 = acc00, acc10 = acc00, acc11 = acc00;

    int K2 = Kh * Kw;
    for (int kk = 0; kk < K2; ++kk) {
        int ki = kk / Kw, kj = kk - ki * Kw;
        size_t offA = pixbase + ((size_t)ki * Win + kj) * Cin;
        const short* wrow = wts + (size_t)kk * N * Cin + (size_t)nr * Cin;
        for (int c0 = 0; c0 < Cin; c0 += 32) {
            bf8 va = *(const bf8*)(in + offA + c0 + kc * 8);
            bf8 vb = *(const bf8*)(wrow + c0 + kc * 8);
            __syncthreads();
            *(bf8*)&sa[lane * 40 + kc * 8] = va;
            *(bf8*)&sb[lane * 40 + kc * 8] = vb;
            __syncthreads();
            bf8 a0 = *(bf8*)&sa[(wm * 32 + (lane & 15)) * 40 + (lane >> 4) * 8];
            bf8 a1 = *(bf8*)&sa[(wm * 32 + 16 + (lane & 15)) * 40 + (lane >> 4) * 8];
            bf8 b0 = *(bf8*)&sb[(wn * 32 + (lane & 15)) * 40 + (lane >> 4) * 8];
            bf8 b1 = *(bf8*)&sb[(wn * 32 + 16 + (lane & 15)) * 40 + (lane >> 4) * 8];
            acc00 = __builtin_amdgcn_mfma_f32_16x16x32_bf16(a0, b0, acc00, 0, 0, 0);
            acc01 = __builtin_amdgcn_mfma_f32_16x16x32_bf16(a0, b1, acc01, 0, 0, 0);
            acc10 = __builtin_amdgcn_mfma_f32_16x16x32_bf16(a1, b0, acc10, 0, 0, 0);
            acc11 = __builtin_amdgcn_mfma_f32_16x16x32_bf16(a1, b1, acc11, 0, 0, 0);
        }
    }

    f4 accs[2][2];
    accs[0][0] = acc00; accs[0][1] = acc01; accs[1][0] = acc10; accs[1][1] = acc11;
#pragma unroll
    for (int i = 0; i < 2; ++i) {
#pragma unroll
        for (int j = 0; j < 2; ++j) {
            int gm_base = m0 + wm * 32 + i * 16 + (lane >> 4) * 4;
            int gn = n0 + wn * 32 + j * 16 + (lane & 15);
            if (gn < N) {
                float bv = bs[gn];
#pragma unroll
                for (int r = 0; r < 4; ++r) {
                    int gm = gm_base + r;
                    if (gm < M) {
                        float v = accs[i][j][r] + bv;
                        if (relu) v = fmaxf(v, 0.f);
                        out[(size_t)gm * N + gn] = f2b(v);
                    }
                }
            }
        }
    }
}

// ---------- conv1 MFMA: x f32 NHWC (287,287,3), 11x11 s2 -> act1 [19321][96] bf16 ----------
// K per ki = 64 (33 real: kj*3+c, rest zero). Wt1[ki][96][64] bf16.
__global__ __launch_bounds__(256) void conv1_mfma_k(
        const float* __restrict__ x, const short* __restrict__ wt1,
        const float* __restrict__ bias, short* __restrict__ out) {
    const int M = 19321, N = 96, Wo = 139;
    __shared__ short sa[64 * 40];
    __shared__ short sb[64 * 40];
    int bid = blockIdx.x;
    int m0 = (bid / 2) * 64, n0 = (bid % 2) * 64;
    int t = threadIdx.x;
    int lane = t & 63;
    int w = t >> 6, wm = w >> 1, wn = w & 1;
    int mr = m0 + lane; if (mr > M - 1) mr = M - 1;
    int oy = mr / Wo, ox = mr - oy * Wo;
    size_t pixbase = ((size_t)(2 * oy) * 287 + 2 * ox) * 3;
    int nr = n0 + lane; if (nr > N - 1) nr = N - 1;
    int kc = t >> 6;

    f4 acc00 = {0.f, 0.f, 0.f, 0.f}, acc01 = acc00, acc10 = acc00, acc11 = acc00;

    for (int ki = 0; ki < 11; ++ki) {
        size_t offA = pixbase + (size_t)ki * 861;
        const short* wrow = wt1 + (size_t)ki * 96 * 64 + (size_t)nr * 64;
        for (int c0 = 0; c0 < 64; c0 += 32) {
            bf8 va;
#pragma unroll
            for (int jj = 0; jj < 8; ++jj) {
                int k = c0 + kc * 8 + jj;
                float xv = (k < 33) ? x[offA + k] : 0.f;
                va[jj] = f2b(xv);
            }
            bf8 vb = *(const bf8*)(wrow + c0 + kc * 8);
            __syncthreads();
            *(bf8*)&sa[lane * 40 + kc * 8] = va;
            *(bf8*)&sb[lane * 40 + kc * 8] = vb;
            __syncthreads();
            bf8 a0 = *(bf8*)&sa[(wm * 32 + (lane & 15)) * 40 + (lane >> 4) * 8];
            bf8 a1 = *(bf8*)&sa[(wm * 32 + 16 + (lane & 15)) * 40 + (lane >> 4) * 8];
            bf8 b0 = *(bf8*)&sb[(wn * 32 + (lane & 15)) * 40 + (lane >> 4) * 8];
            bf8 b1 = *(bf8*)&sb[(wn * 32 + 16 + (lane & 15)) * 40 + (lane >> 4) * 8];
            acc00 = __builtin_amdgcn_mfma_f32_16x16x32_bf16(a0, b0, acc00, 0, 0, 0);
            acc01 = __builtin_amdgcn_mfma_f32_16x16x32_bf16(a0, b1, acc01, 0, 0, 0);
            acc10 = __builtin_amdgcn_mfma_f32_16x16x32_bf16(a1, b0, acc10, 0, 0, 0);
            acc11 = __builtin_amdgcn_mfma_f32_16x16x32_bf16(a1, b1, acc11, 0, 0, 0);
        }
    }

    f4 accs[2][2];
    accs[0][0] = acc00; accs[0][1] = acc01; accs[1][0] = acc10; accs[1][1] = acc11;
#pragma unroll
    for (int i = 0; i < 2; ++i) {
#pragma unroll
        for (int j = 0; j < 2; ++j) {
            int gm_base = m0 + wm * 32 + i * 16 + (lane >> 4) * 4;
            int gn = n0 + wn * 32 + j * 16 + (lane & 15);
            if (gn < N) {
                float bv = bias[gn];
#pragma unroll
                for (int r = 0; r < 4; ++r) {
                    int gm = gm_base + r;
                    if (gm < M)
                        out[(size_t)gm * N + gn] = f2b(accs[i][j][r] + bv);
                }
            }
        }
    }
}

// ---------- maxpool 3x3 s2 + relu, NHWC bf16 ----------
__global__ void pool_k(const short* __restrict__ in, short* __restrict__ out,
                       int C8, int Win, int Ho) {
    int idx = blockIdx.x * blockDim.x + threadIdx.x;
    int total = Ho * Ho * C8;
    if (idx >= total) return;
    int c8 = idx % C8;
    int p = idx / C8;
    int oy = p / Ho, ox = p % Ho;
    int C = C8 * 8;
    float mx[8];
#pragma unroll
    for (int e = 0; e < 8; ++e) mx[e] = -INFINITY;
#pragma unroll
    for (int ki = 0; ki < 3; ++ki)
#pragma unroll
        for (int kj = 0; kj < 3; ++kj) {
            const bf8 v = *(const bf8*)(in + ((size_t)(oy * 2 + ki) * Win + ox * 2 + kj) * C + c8 * 8);
#pragma unroll
            for (int e = 0; e < 8; ++e) mx[e] = fmaxf(mx[e], b2f((unsigned short)v[e]));
        }
    bf8 o;
#pragma unroll
    for (int e = 0; e < 8; ++e) o[e] = f2b(fmaxf(mx[e], 0.f));
    *(bf8*)(out + (size_t)p * C + c8 * 8) = o;
}

// ---------- depthwise 4x4 correlation, NHWC ----------
// in: crc section base (stride 512), z: [8][256][16] f32, out: corr section [3528+pad][256]
__global__ void dwcorr_k(const short* __restrict__ in, const float* __restrict__ z,
                         short* __restrict__ out) {
    int idx = blockIdx.x * blockDim.x + threadIdx.x;
    if (idx >= 8 * 441 * 256) return;
    int c = idx & 255;
    int l = (idx >> 8) % 441;
    int mb = idx / (441 * 256);
    int y = l / 21, x = l % 21;
    const float* zp = z + ((size_t)mb * 256 + c) * 16;
    float acc = 0.f;
#pragma unroll
    for (int ki = 0; ki < 4; ++ki)
#pragma unroll
        for (int kj = 0; kj < 4; ++kj)
            acc = fmaf(b2f((unsigned short)in[((size_t)((y + ki) * 24 + x + kj)) * 512 + c]),
                       zp[ki * 4 + kj], acc);
    out[((size_t)mb * 441 + l) * 256 + c] = f2b(acc);
}

// ---------- head layer-2: hid bf16 [7168][256] -> cls2 [3528][10], reg2 [3528][20] f32 ----------
__global__ void head2_k(const short* __restrict__ hid,
                        const float* __restrict__ chw2, const float* __restrict__ chb2,
                        const float* __restrict__ rhw2, const float* __restrict__ rhb2,
                        float* __restrict__ cls2, float* __restrict__ reg2) {
    int idx = blockIdx.x * blockDim.x + threadIdx.x;
    if (idx >= 35280 + 70560) return;
    const short* h;
    const float* wp;
    float acc;
    float* op;
    if (idx < 35280) {
        int ml = idx / 10, o = idx % 10;
        h = hid + (size_t)ml * 256;
        wp = chw2 + o * 256;
        acc = chb2[o];
        op = cls2 + idx;
    } else {
        int j = idx - 35280;
        int ml = j / 20, o = j % 20;
        h = hid + (size_t)(3584 + ml) * 256;
        wp = rhw2 + o * 256;
        acc = rhb2[o];
        op = reg2 + j;
    }
    for (int c = 0; c < 256; c += 8) {
        bf8 hv = *(const bf8*)(h + c);
#pragma unroll
        for (int e = 0; e < 8; ++e)
            acc = fmaf(b2f((unsigned short)hv[e]), wp[c + e], acc);
    }
    *op = acc;
}

// ---------- epilogue ----------
// cls2: [3528][10], reg2: [3528][20] (ml = m*441+pos)
__global__ void epilogue_k(const float* __restrict__ cls2, const float* __restrict__ reg2,
                           const float* __restrict__ a0, const float* __restrict__ a1,
                           const float* __restrict__ a2, const float* __restrict__ a3,
                           float* __restrict__ out) {
    const int Ntot = 8 * 2205;
    int idx = blockIdx.x * blockDim.x + threadIdx.x;
    if (idx >= Ntot) return;
    int m = idx / 2205, j = idx % 2205;
    int a = j / 441, pos = j % 441;
    int ml = m * 441 + pos;
    float c0 = cls2[ml * 10 + a];
    float c1 = cls2[ml * 10 + 5 + a];
    float s1 = 1.f / (1.f + expf(c0 - c1));
    float dl0 = reg2[ml * 20 + a];
    float dl1 = reg2[ml * 20 + 5 + a];
    float dl2 = reg2[ml * 20 + 10 + a];
    float dl3 = reg2[ml * 20 + 15 + a];
    float A2 = a2[idx], A3 = a3[idx];
    out[0 * Ntot + idx] = fmaf(dl0, A2, a0[idx]);
    out[1 * Ntot + idx] = fmaf(dl1, A3, a1[idx]);
    out[2 * Ntot + idx] = expf(dl2) * A2;
    out[3 * Ntot + idx] = expf(dl3) * A3;
    out[4 * Ntot + idx] = s1;
}

extern "C" void kernel_launch(void* const* d_in, const int* in_sizes, int n_in,
                              void* d_out, int out_size, void* d_ws, size_t ws_size,
                              hipStream_t stream) {
    const float* x     = (const float*)d_in[0];
    const float* z_reg = (const float*)d_in[1];
    const float* z_cls = (const float*)d_in[2];
    const float* bb_w1 = (const float*)d_in[3];
    const float* bb_b1 = (const float*)d_in[4];
    const float* bb_w2 = (const float*)d_in[5];
    const float* bb_b2 = (const float*)d_in[6];
    const float* bb_w3 = (const float*)d_in[7];
    const float* bb_b3 = (const float*)d_in[8];
    const float* bb_w4 = (const float*)d_in[9];
    const float* bb_b4 = (const float*)d_in[10];
    const float* bb_w5 = (const float*)d_in[11];
    const float* bb_b5 = (const float*)d_in[12];
    const float* wr    = (const float*)d_in[13];
    const float* br    = (const float*)d_in[14];
    const float* wc    = (const float*)d_in[15];
    const float* bc    = (const float*)d_in[16];
    const float* rh_w1 = (const float*)d_in[17];
    const float* rh_b1 = (const float*)d_in[18];
    const float* rh_w2 = (const float*)d_in[19];
    const float* rh_b2 = (const float*)d_in[20];
    const float* ch_w1 = (const float*)d_in[21];
    const float* ch_b1 = (const float*)d_in[22];
    const float* ch_w2 = (const float*)d_in[23];
    const float* ch_b2 = (const float*)d_in[24];
    const float* anc0  = (const float*)d_in[25];
    const float* anc1  = (const float*)d_in[26];
    const float* anc2  = (const float*)d_in[27];
    const float* anc3  = (const float*)d_in[28];

    // ---- workspace layout (shorts) ----
    short* sws = (short*)d_ws;
    short* Wt    = sws;                       // 1,327,104 (max weight scratch, conv4)
    short* act1  = Wt + 1327104;              // 19321*96 = 1,854,816
    short* pool1 = act1 + 1854816;            // 4761*96  =   457,056
    short* act2  = pool1 + 457056;            // 4225*256 = 1,081,600
    short* pool2 = act2 + 1081600;            // 1024*256 =   262,144
    short* act3  = pool2 + 262144;            // 900*384  =   345,600
    short* act4  = act3 + 345600;             // 784*384  =   301,056
    short* xf    = act4 + 301056;             // 676*256  =   173,056
    short* crc   = xf + 173056;               // 576*512  =   294,912
    short* corr  = crc + 294912;              // 7168*256 = 1,835,008
    short* hid   = corr + 1835008;            // 7168*256 = 1,835,008
    float* fws   = (float*)(hid + 1835008);
    float* bcat  = fws;                       // 512
    float* bcat2 = bcat + 512;                // 512
    float* cls2  = bcat2 + 512;               // 35,280
    float* reg2  = cls2 + 35280;              // 70,560

    const int BIG = 1 << 30;

    // conv1
    wconv1_k<<<cdiv(11 * 96 * 64, TPB), TPB, 0, stream>>>(bb_w1, Wt);
    conv1_mfma_k<<<303 * 2, 256, 0, stream>>>(x, Wt, bb_b1, act1);
    pool_k<<<cdiv(69 * 69 * 12, TPB), TPB, 0, stream>>>(act1, pool1, 12, 139, 69);

    // conv2: M=4225 N=256 Cin=96 K=5x5
    wconv_k<<<cdiv(256 * 96 * 25, TPB), TPB, 0, stream>>>(bb_w2, Wt, 256, 96, 25, 256, 0);
    gemm_conv_k<<<67 * 4, 256, 0, stream>>>(pool1, Wt, bb_b2, act2,
        4225, 256, 96, 69, 65, 5, 5, 0, BIG, 0, 0, 4);
    pool_k<<<cdiv(32 * 32 * 32, TPB), TPB, 0, stream>>>(act2, pool2, 32, 65, 32);

    // conv3: M=900 N=384 Cin=256
    wconv_k<<<cdiv(384 * 256 * 9, TPB), TPB, 0, stream>>>(bb_w3, Wt, 384, 256, 9, 384, 0);
    gemm_conv_k<<<15 * 6, 256, 0, stream>>>(pool2, Wt, bb_b3, act3,
        900, 384, 256, 32, 30, 3, 3, 1, BIG, 0, 0, 6);

    // conv4: M=784 N=384 Cin=384
    wconv_k<<<cdiv(384 * 384 * 9, TPB), TPB, 0, stream>>>(bb_w4, Wt, 384, 384, 9, 384, 0);
    gemm_conv_k<<<13 * 6, 256, 0, stream>>>(act3, Wt, bb_b4, act4,
        784, 384, 384, 30, 28, 3, 3, 1, BIG, 0, 0, 6);

    // conv5: M=676 N=256 Cin=384 (no relu)
    wconv_k<<<cdiv(256 * 384 * 9, TPB), TPB, 0, stream>>>(bb_w5, Wt, 256, 384, 9, 256, 0);
    gemm_conv_k<<<11 * 4, 256, 0, stream>>>(act4, Wt, bb_b5, xf,
        676, 256, 384, 28, 26, 3, 3, 0, BIG, 0, 0, 4);

    // conv_reg2/conv_cls2 fused: N=512 (cols 0..255 = wr -> c_x, 256..511 = wc -> r_x)
    wconv_k<<<cdiv(256 * 256 * 9, TPB), TPB, 0, stream>>>(wr, Wt, 256, 256, 9, 512, 0);
    wconv_k<<<cdiv(256 * 256 * 9, TPB), TPB, 0, stream>>>(wc, Wt, 256, 256, 9, 512, 256);
    copy_biases_k<<<4, 256, 0, stream>>>(br, bc, ch_b1, rh_b1, bcat, bcat2);
    gemm_conv_k<<<9 * 8, 256, 0, stream>>>(xf, Wt, bcat, crc,
        576, 512, 256, 26, 24, 3, 3, 1, BIG, 0, 0, 8);

    // depthwise correlation: c_x (crc cols 0..255) x z_cls -> corr rows 0..3527
    //                        r_x (crc cols 256..511) x z_reg -> corr rows 3584..7111
    dwcorr_k<<<cdiv(8 * 441 * 256, TPB), TPB, 0, stream>>>(crc, z_cls, corr);
    dwcorr_k<<<cdiv(8 * 441 * 256, TPB), TPB, 0, stream>>>(crc + 256, z_reg, corr + (size_t)3584 * 256);

    // head layer-1 (1x1, K=256), M-concat with section split at 3584
    wconv_k<<<cdiv(256 * 256, TPB), TPB, 0, stream>>>(ch_w1, Wt, 256, 256, 1, 256, 0);
    wconv_k<<<cdiv(256 * 256, TPB), TPB, 0, stream>>>(rh_w1, Wt + 65536, 256, 256, 1, 256, 0);
    gemm_conv_k<<<112 * 4, 256, 0, stream>>>(corr, Wt, bcat2, hid,
        7112, 256, 256, 7112, 7112, 1, 1, 1, 3584, 65536, 256, 4);

    // head layer-2 + decode
    head2_k<<<cdiv(35280 + 70560, TPB), TPB, 0, stream>>>(hid, ch_w2, ch_b2, rh_w2, rh_b2, cls2, reg2);
    epilogue_k<<<cdiv(8 * 2205, TPB), TPB, 0, stream>>>(cls2, reg2, anc0, anc1, anc2, anc3,
                                                        (float*)d_out);
}

// Round 4
// 302.543 us; speedup vs baseline: 7.9385x; 1.1962x over previous
//
#include <hip/hip_runtime.h>
#include <math.h>

#define TPB 256
static inline int cdiv(int a, int b) { return (a + b - 1) / b; }

typedef short bf8 __attribute__((ext_vector_type(8)));   // 8 bf16 (4 VGPRs)
typedef float f4 __attribute__((ext_vector_type(4)));    // mfma acc

__device__ inline float b2f(unsigned short u) {
    union { unsigned int i; float f; } v; v.i = ((unsigned int)u) << 16; return v.f;
}
__device__ inline short f2b(float f) {
    union { float f; unsigned int u; } v; v.f = f;
    unsigned int r = v.u + 0x7FFF + ((v.u >> 16) & 1);
    return (short)(r >> 16);
}

// ---------- weight convert: W[O][C][Kh][Kw] f32 -> Wt[ki][Ot][Kw*C] bf16 ----------
__global__ void wconv_k(const float* __restrict__ in, short* __restrict__ out,
                        int O, int C, int Kh, int Kw, int Ot, int ooff) {
    int K2 = Kh * Kw;
    int idx = blockIdx.x * blockDim.x + threadIdx.x;
    if (idx >= O * C * K2) return;
    int c = idx % C;
    int o = (idx / C) % O;
    int kk = idx / (C * O);
    int ki = kk / Kw, kj = kk % Kw;
    out[((size_t)ki * Ot + ooff + o) * (Kw * C) + kj * C + c] =
        f2b(in[((size_t)o * C + c) * K2 + kk]);
}

// ---------- conv1 weights: W[96][3][11][11] -> Wt1[ki][96][64], k=kj*3+c, zero-pad ----------
__global__ void wconv1_k(const float* __restrict__ in, short* __restrict__ out) {
    int idx = blockIdx.x * blockDim.x + threadIdx.x;
    if (idx >= 11 * 96 * 64) return;
    int k = idx % 64;
    int o = (idx / 64) % 96;
    int ki = idx / (64 * 96);
    float v = 0.f;
    if (k < 33) {
        int kj = k / 3, c = k % 3;
        v = in[o * 363 + c * 121 + ki * 11 + kj];
    }
    out[idx] = f2b(v);
}

// ---------- bias concat helper ----------
__global__ void copy_biases_k(const float* br, const float* bc, const float* chb1,
                              const float* rhb1, float* bcat, float* bcat2) {
    int t = blockIdx.x * blockDim.x + threadIdx.x;
    if (t < 256) bcat[t] = br[t];
    else if (t < 512) bcat[t] = bc[t - 256];
    else if (t < 768) bcat2[t - 512] = chb1[t - 512];
    else if (t < 1024) bcat2[t - 768 + 256] = rhb1[t - 768];
}

// ---------- double-buffered implicit-GEMM conv (bf16 MFMA) ----------
// MODE 0: in = NHWC bf16. MODE 1: conv1 (in = f32 x, K-row = 33 padded to 64).
// wt: [ki][N][KwC] bf16. out: [M][N] bf16. Block 64m x 64n, 4 waves (2x2) of 32x32.
// One barrier per BK-step; global prefetch of step s+1 issued before MFMAs of step s.
template <int BKC, int MODE>
__global__ __launch_bounds__(256) void gemm_dbuf_k(
        const short* __restrict__ in, const short* __restrict__ wt,
        const float* __restrict__ bias, short* __restrict__ out,
        int M, int N, int Wo, int Cin, int Win,
        int S, int SPR, int aWrap, int bWrap, int KwC,
        int relu, int msplit, int wsec, int bsec, int nt) {
    constexpr int BK = BKC * 32;
    constexpr int LDW = BK + 8;
    __shared__ short sa[2][64 * LDW];
    __shared__ short sb[2][64 * LDW];

    int bid = blockIdx.x;
    int m0 = (bid / nt) * 64, n0 = (bid % nt) * 64;
    int t = threadIdx.x;
    int lane = t & 63;
    int wid = t >> 6;
    int wm = wid >> 1, wn = wid & 1;
    int sec = (m0 >= msplit) ? 1 : 0;
    const short* wts = wt + (size_t)sec * wsec;
    const float* bs = bias + sec * bsec;

    int mr = m0 + lane; if (mr > M - 1) mr = M - 1;
    int oy = mr / Wo, ox = mr - oy * Wo;
    int nr = n0 + lane; if (nr > N - 1) nr = N - 1;

    const short* pA = in;         // MODE 0
    const float* pX = nullptr;    // MODE 1
    if (MODE == 0) pA = in + ((size_t)oy * Win + ox) * Cin + wid * 8;
    else           pX = (const float*)in + ((size_t)(2 * oy) * 287 + 2 * ox) * 3;
    const short* pB = wts + (size_t)nr * KwC + wid * 8;

    int wl = lane * LDW + wid * 8;
    int arow = (wm * 32 + (lane & 15)) * LDW + (lane >> 4) * 8;
    int brow = (wn * 32 + (lane & 15)) * LDW + (lane >> 4) * 8;

    f4 acc[2][2] = {};
    bf8 va[BKC], vb[BKC];
    int srow = 0;

#define LOAD_STEP()                                                          \
    do {                                                                     \
        if (MODE == 0) {                                                     \
            _Pragma("unroll")                                                \
            for (int j = 0; j < BKC; ++j) {                                  \
                va[j] = *(const bf8*)(pA + j * 32);                          \
                vb[j] = *(const bf8*)(pB + j * 32);                          \
            }                                                                \
        } else {                                                             \
            _Pragma("unroll")                                                \
            for (int j = 0; j < BKC; ++j) {                                  \
                _Pragma("unroll")                                            \
                for (int e = 0; e < 8; ++e) {                                \
                    int k = wid * 8 + j * 32 + e;                            \
                    va[j][e] = f2b((k < 33) ? pX[k] : 0.f);                  \
                }                                                            \
                vb[j] = *(const bf8*)(pB + j * 32);                          \
            }                                                                \
        }                                                                    \
        if (++srow == SPR) {                                                 \
            srow = 0;                                                        \
            if (MODE == 0) pA += aWrap; else pX += aWrap;                    \
            pB += bWrap;                                                     \
        } else {                                                             \
            if (MODE == 0) pA += BK;                                         \
            pB += BK;                                                        \
        }                                                                    \
    } while (0)

    // prologue: stage step 0
    LOAD_STEP();
#pragma unroll
    for (int j = 0; j < BKC; ++j) {
        *(bf8*)&sa[0][wl + j * 32] = va[j];
        *(bf8*)&sb[0][wl + j * 32] = vb[j];
    }
    __syncthreads();

    for (int s = 0; s < S; ++s) {
        int cur = s & 1;
        bool pre = (s + 1 < S);
        if (pre) LOAD_STEP();
        const short* A = sa[cur];
        const short* B = sb[cur];
#pragma unroll
        for (int kc = 0; kc < BKC; ++kc) {
            bf8 a0 = *(const bf8*)&A[arow + kc * 32];
            bf8 a1 = *(const bf8*)&A[arow + 16 * LDW + kc * 32];
            bf8 b0 = *(const bf8*)&B[brow + kc * 32];
            bf8 b1 = *(const bf8*)&B[brow + 16 * LDW + kc * 32];
            acc[0][0] = __builtin_amdgcn_mfma_f32_16x16x32_bf16(a0, b0, acc[0][0], 0, 0, 0);
            acc[0][1] = __builtin_amdgcn_mfma_f32_16x16x32_bf16(a0, b1, acc[0][1], 0, 0, 0);
            acc[1][0] = __builtin_amdgcn_mfma_f32_16x16x32_bf16(a1, b0, acc[1][0], 0, 0, 0);
            acc[1][1] = __builtin_amdgcn_mfma_f32_16x16x32_bf16(a1, b1, acc[1][1], 0, 0, 0);
        }
        if (pre) {
            int nb = cur ^ 1;
#pragma unroll
            for (int j = 0; j < BKC; ++j) {
                *(bf8*)&sa[nb][wl + j * 32] = va[j];
                *(bf8*)&sb[nb][wl + j * 32] = vb[j];
            }
        }
        __syncthreads();
    }
#undef LOAD_STEP

#pragma unroll
    for (int i = 0; i < 2; ++i) {
#pragma unroll
        for (int j = 0; j < 2; ++j) {
            int gm_base = m0 + wm * 32 + i * 16 + (lane >> 4) * 4;
            int gn = n0 + wn * 32 + j * 16 + (lane & 15);
            if (gn < N) {
                float bv = bs[gn];
#pragma unroll
                for (int r = 0; r < 4; ++r) {
                    int gm = gm_base + r;
                    if (gm < M) {
                        float v = acc[i][j][r] + bv;
                        if (relu) v = fmaxf(v, 0.f);
                        out[(size_t)gm * N + gn] = f2b(v);
                    }
                }
            }
        }
    }
}

// ---------- maxpool 3x3 s2 + relu, NHWC bf16 ----------
__global__ void pool_k(const short* __restrict__ in, short* __restrict__ out,
                       int C8, int Win, int Ho) {
    int idx = blockIdx.x * blockDim.x + threadIdx.x;
    int total = Ho * Ho * C8;
    if (idx >= total) return;
    int c8 = idx % C8;
    int p = idx / C8;
    int oy = p / Ho, ox = p % Ho;
    int C = C8 * 8;
    float mx[8];
#pragma unroll
    for (int e = 0; e < 8; ++e) mx[e] = -INFINITY;
#pragma unroll
    for (int ki = 0; ki < 3; ++ki)
#pragma unroll
        for (int kj = 0; kj < 3; ++kj) {
            const bf8 v = *(const bf8*)(in + ((size_t)(oy * 2 + ki) * Win + ox * 2 + kj) * C + c8 * 8);
#pragma unroll
            for (int e = 0; e < 8; ++e) mx[e] = fmaxf(mx[e], b2f((unsigned short)v[e]));
        }
    bf8 o;
#pragma unroll
    for (int e = 0; e < 8; ++e) o[e] = f2b(fmaxf(mx[e], 0.f));
    *(bf8*)(out + (size_t)p * C + c8 * 8) = o;
}

// ---------- depthwise 4x4 correlation, NHWC ----------
__global__ void dwcorr_k(const short* __restrict__ in, const float* __restrict__ z,
                         short* __restrict__ out) {
    int idx = blockIdx.x * blockDim.x + threadIdx.x;
    if (idx >= 8 * 441 * 256) return;
    int c = idx & 255;
    int l = (idx >> 8) % 441;
    int mb = idx / (441 * 256);
    int y = l / 21, x = l % 21;
    const float* zp = z + ((size_t)mb * 256 + c) * 16;
    float acc = 0.f;
#pragma unroll
    for (int ki = 0; ki < 4; ++ki)
#pragma unroll
        for (int kj = 0; kj < 4; ++kj)
            acc = fmaf(b2f((unsigned short)in[((size_t)((y + ki) * 24 + x + kj)) * 512 + c]),
                       zp[ki * 4 + kj], acc);
    out[((size_t)mb * 441 + l) * 256 + c] = f2b(acc);
}

// ---------- head layer-2 ----------
__global__ void head2_k(const short* __restrict__ hid,
                        const float* __restrict__ chw2, const float* __restrict__ chb2,
                        const float* __restrict__ rhw2, const float* __restrict__ rhb2,
                        float* __restrict__ cls2, float* __restrict__ reg2) {
    int idx = blockIdx.x * blockDim.x + threadIdx.x;
    if (idx >= 35280 + 70560) return;
    const short* h;
    const float* wp;
    float acc;
    float* op;
    if (idx < 35280) {
        int ml = idx / 10, o = idx % 10;
        h = hid + (size_t)ml * 256;
        wp = chw2 + o * 256;
        acc = chb2[o];
        op = cls2 + idx;
    } else {
        int j = idx - 35280;
        int ml = j / 20, o = j % 20;
        h = hid + (size_t)(3584 + ml) * 256;
        wp = rhw2 + o * 256;
        acc = rhb2[o];
        op = reg2 + j;
    }
    for (int c = 0; c < 256; c += 8) {
        bf8 hv = *(const bf8*)(h + c);
#pragma unroll
        for (int e = 0; e < 8; ++e)
            acc = fmaf(b2f((unsigned short)hv[e]), wp[c + e], acc);
    }
    *op = acc;
}

// ---------- epilogue ----------
__global__ void epilogue_k(const float* __restrict__ cls2, const float* __restrict__ reg2,
                           const float* __restrict__ a0, const float* __restrict__ a1,
                           const float* __restrict__ a2, const float* __restrict__ a3,
                           float* __restrict__ out) {
    const int Ntot = 8 * 2205;
    int idx = blockIdx.x * blockDim.x + threadIdx.x;
    if (idx >= Ntot) return;
    int m = idx / 2205, j = idx % 2205;
    int a = j / 441, pos = j % 441;
    int ml = m * 441 + pos;
    float c0 = cls2[ml * 10 + a];
    float c1 = cls2[ml * 10 + 5 + a];
    float s1 = 1.f / (1.f + expf(c0 - c1));
    float dl0 = reg2[ml * 20 + a];
    float dl1 = reg2[ml * 20 + 5 + a];
    float dl2 = reg2[ml * 20 + 10 + a];
    float dl3 = reg2[ml * 20 + 15 + a];
    float A2 = a2[idx], A3 = a3[idx];
    out[0 * Ntot + idx] = fmaf(dl0, A2, a0[idx]);
    out[1 * Ntot + idx] = fmaf(dl1, A3, a1[idx]);
    out[2 * Ntot + idx] = expf(dl2) * A2;
    out[3 * Ntot + idx] = expf(dl3) * A3;
    out[4 * Ntot + idx] = s1;
}

extern "C" void kernel_launch(void* const* d_in, const int* in_sizes, int n_in,
                              void* d_out, int out_size, void* d_ws, size_t ws_size,
                              hipStream_t stream) {
    const float* x     = (const float*)d_in[0];
    const float* z_reg = (const float*)d_in[1];
    const float* z_cls = (const float*)d_in[2];
    const float* bb_w1 = (const float*)d_in[3];
    const float* bb_b1 = (const float*)d_in[4];
    const float* bb_w2 = (const float*)d_in[5];
    const float* bb_b2 = (const float*)d_in[6];
    const float* bb_w3 = (const float*)d_in[7];
    const float* bb_b3 = (const float*)d_in[8];
    const float* bb_w4 = (const float*)d_in[9];
    const float* bb_b4 = (const float*)d_in[10];
    const float* bb_w5 = (const float*)d_in[11];
    const float* bb_b5 = (const float*)d_in[12];
    const float* wr    = (const float*)d_in[13];
    const float* br    = (const float*)d_in[14];
    const float* wc    = (const float*)d_in[15];
    const float* bc    = (const float*)d_in[16];
    const float* rh_w1 = (const float*)d_in[17];
    const float* rh_b1 = (const float*)d_in[18];
    const float* rh_w2 = (const float*)d_in[19];
    const float* rh_b2 = (const float*)d_in[20];
    const float* ch_w1 = (const float*)d_in[21];
    const float* ch_b1 = (const float*)d_in[22];
    const float* ch_w2 = (const float*)d_in[23];
    const float* ch_b2 = (const float*)d_in[24];
    const float* anc0  = (const float*)d_in[25];
    const float* anc1  = (const float*)d_in[26];
    const float* anc2  = (const float*)d_in[27];
    const float* anc3  = (const float*)d_in[28];

    // ---- workspace layout (shorts) ----
    short* sws = (short*)d_ws;
    short* Wt    = sws;                       // 1,327,104 (max: conv4 [3][384][1152])
    short* act1  = Wt + 1327104;              // 19321*96
    short* pool1 = act1 + 1854816;            // 4761*96
    short* act2  = pool1 + 457056;            // 4225*256
    short* pool2 = act2 + 1081600;            // 1024*256
    short* act3  = pool2 + 262144;            // 900*384
    short* act4  = act3 + 345600;             // 784*384
    short* xf    = act4 + 301056;             // 676*256
    short* crc   = xf + 173056;               // 576*512
    short* corr  = crc + 294912;              // 7168*256
    short* hid   = corr + 1835008;            // 7168*256
    float* fws   = (float*)(hid + 1835008);
    float* bcat  = fws;                       // 512
    float* bcat2 = bcat + 512;                // 512
    float* cls2  = bcat2 + 512;               // 35,280
    float* reg2  = cls2 + 35280;              // 70,560

    const int BIG = 1 << 30;

    // conv1: M=19321 N=96 (2 n-tiles, masked), Kh=11, K-row 64 (padded 33), S=11
    wconv1_k<<<cdiv(11 * 96 * 64, TPB), TPB, 0, stream>>>(bb_w1, Wt);
    gemm_dbuf_k<2, 1><<<303 * 2, 256, 0, stream>>>(
        (const short*)x, Wt, bb_b1, act1,
        19321, 96, 139, 3, 287,
        11, 1, 861, 96 * 64, 64, 0, BIG, 0, 0, 2);
    pool_k<<<cdiv(69 * 69 * 12, TPB), TPB, 0, stream>>>(act1, pool1, 12, 139, 69);

    // conv2: M=4225 N=256 Cin=96 KwC=480, BK=96, SPR=5, S=25
    wconv_k<<<cdiv(256 * 96 * 25, TPB), TPB, 0, stream>>>(bb_w2, Wt, 256, 96, 5, 5, 256, 0);
    gemm_dbuf_k<3, 0><<<67 * 4, 256, 0, stream>>>(
        pool1, Wt, bb_b2, act2,
        4225, 256, 65, 96, 69,
        25, 5, 69 * 96 - 480 + 96, 255 * 480 + 96, 480, 0, BIG, 0, 0, 4);
    pool_k<<<cdiv(32 * 32 * 32, TPB), TPB, 0, stream>>>(act2, pool2, 32, 65, 32);

    // conv3: M=900 N=384 Cin=256 KwC=768, BK=64, SPR=12, S=36
    wconv_k<<<cdiv(384 * 256 * 9, TPB), TPB, 0, stream>>>(bb_w3, Wt, 384, 256, 3, 3, 384, 0);
    gemm_dbuf_k<2, 0><<<15 * 6, 256, 0, stream>>>(
        pool2, Wt, bb_b3, act3,
        900, 384, 30, 256, 32,
        36, 12, 32 * 256 - 768 + 64, 383 * 768 + 64, 768, 1, BIG, 0, 0, 6);

    // conv4: M=784 N=384 Cin=384 KwC=1152, SPR=18, S=54
    wconv_k<<<cdiv(384 * 384 * 9, TPB), TPB, 0, stream>>>(bb_w4, Wt, 384, 384, 3, 3, 384, 0);
    gemm_dbuf_k<2, 0><<<13 * 6, 256, 0, stream>>>(
        act3, Wt, bb_b4, act4,
        784, 384, 28, 384, 30,
        54, 18, 30 * 384 - 1152 + 64, 383 * 1152 + 64, 1152, 1, BIG, 0, 0, 6);

    // conv5: M=676 N=256 Cin=384, S=54 (no relu)
    wconv_k<<<cdiv(256 * 384 * 9, TPB), TPB, 0, stream>>>(bb_w5, Wt, 256, 384, 3, 3, 256, 0);
    gemm_dbuf_k<2, 0><<<11 * 4, 256, 0, stream>>>(
        act4, Wt, bb_b5, xf,
        676, 256, 26, 384, 28,
        54, 18, 28 * 384 - 1152 + 64, 255 * 1152 + 64, 1152, 0, BIG, 0, 0, 4);

    // conv_reg2/conv_cls2 fused: N=512, Cin=256, KwC=768, S=36
    wconv_k<<<cdiv(256 * 256 * 9, TPB), TPB, 0, stream>>>(wr, Wt, 256, 256, 3, 3, 512, 0);
    wconv_k<<<cdiv(256 * 256 * 9, TPB), TPB, 0, stream>>>(wc, Wt, 256, 256, 3, 3, 512, 256);
    copy_biases_k<<<4, 256, 0, stream>>>(br, bc, ch_b1, rh_b1, bcat, bcat2);
    gemm_dbuf_k<2, 0><<<9 * 8, 256, 0, stream>>>(
        xf, Wt, bcat, crc,
        576, 512, 24, 256, 26,
        36, 12, 26 * 256 - 768 + 64, 511 * 768 + 64, 768, 1, BIG, 0, 0, 8);

    // depthwise correlation
    dwcorr_k<<<cdiv(8 * 441 * 256, TPB), TPB, 0, stream>>>(crc, z_cls, corr);
    dwcorr_k<<<cdiv(8 * 441 * 256, TPB), TPB, 0, stream>>>(crc + 256, z_reg, corr + (size_t)3584 * 256);

    // head layer-1 (1x1, K=256), M-concat split at 3584, S=4
    wconv_k<<<cdiv(256 * 256, TPB), TPB, 0, stream>>>(ch_w1, Wt, 256, 256, 1, 1, 256, 0);
    wconv_k<<<cdiv(256 * 256, TPB), TPB, 0, stream>>>(rh_w1, Wt + 65536, 256, 256, 1, 1, 256, 0);
    gemm_dbuf_k<2, 0><<<112 * 4, 256, 0, stream>>>(
        corr, Wt, bcat2, hid,
        7112, 256, 7112, 256, 7112,
        4, 4, 0, 255 * 256 + 64, 256, 1, 3584, 65536, 256, 4);

    // head layer-2 + decode
    head2_k<<<cdiv(35280 + 70560, TPB), TPB, 0, stream>>>(hid, ch_w2, ch_b2, rh_w2, rh_b2, cls2, reg2);
    epilogue_k<<<cdiv(8 * 2205, TPB), TPB, 0, stream>>>(cls2, reg2, anc0, anc1, anc2, anc3,
                                                        (float*)d_out);
}

// Round 5
// 185.038 us; speedup vs baseline: 12.9797x; 1.6350x over previous
//
#include <hip/hip_runtime.h>
#include <math.h>

#define TPB 256
static inline int cdiv(int a, int b) { return (a + b - 1) / b; }

typedef short bf8 __attribute__((ext_vector_type(8)));   // 8 bf16 (4 VGPRs)
typedef float f4 __attribute__((ext_vector_type(4)));    // mfma acc

__device__ inline float b2f(unsigned short u) {
    union { unsigned int i; float f; } v; v.i = ((unsigned int)u) << 16; return v.f;
}
__device__ inline short f2b(float f) {
    union { float f; unsigned int u; } v; v.f = f;
    unsigned int r = v.u + 0x7FFF + ((v.u >> 16) & 1);
    return (short)(r >> 16);
}

// ---------------- workspace offsets (in shorts) ----------------
#define OW1   0               // [11][96][64]      conv1 weights (K=kj*3+c, pad 33->64)
#define OW2   67584           // [5][256][512]     conv2 (480 pad 512)
#define OW3   722944          // [3][384][768]     conv3
#define OW4   1607680         // [3][384][1152]    conv4
#define OW5   2934784         // [3][256][1152]    conv5
#define OWRC  3819520         // [3][512][768]     wr|wc fused
#define OWH1  4999168         // 2 x [256][256]    ch_w1 | rh_w1
#define OZT   5130240         // 2 x [8][16][256]  z_cls | z_reg transposed, bf16
#define NWELEM 5195776
#define OBIAS 5195776         // 1024 f32 (2048 shorts): br|bc|chb1|rhb1
#define OACT1 5197824         // 19321*96 (+slack)  act1, later reused as hid
#define OP1   7054688         // 4761*96 (+slack)
#define OACTB 7513792         // 1,998,592 region: xb / act2|pool2|act3|act4 / corr
#define OXF   9512384         // 676*256 (+slack)
#define OCRC  9687488         // 576*512 (+slack); later reused for cls2/reg2 f32

#define XB_OFF    0
#define ACT2_OFF  0
#define POOL2_OFF 1083648
#define ACT3_OFF  1347840
#define ACT4_OFF  1695488
#define CORR_OFF  0

// ---------------- fused prep: all weight layouts + biases + z-transpose + x->bf16 ----------------
__global__ void wprep_k(const float* __restrict__ bb_w1, const float* __restrict__ bb_w2,
                        const float* __restrict__ bb_w3, const float* __restrict__ bb_w4,
                        const float* __restrict__ bb_w5,
                        const float* __restrict__ wr, const float* __restrict__ wc,
                        const float* __restrict__ ch_w1, const float* __restrict__ rh_w1,
                        const float* __restrict__ z_cls, const float* __restrict__ z_reg,
                        const float* __restrict__ br, const float* __restrict__ bc,
                        const float* __restrict__ chb1, const float* __restrict__ rhb1,
                        const float* __restrict__ x,
                        short* __restrict__ W, float* __restrict__ biasf,
                        short* __restrict__ xb) {
    int idx = blockIdx.x * blockDim.x + threadIdx.x;
    if (idx < 67584) {                               // Wt1 [11][96][64]
        int k = idx & 63, o = (idx >> 6) % 96, ki = idx / (64 * 96);
        float v = 0.f;
        if (k < 33) v = bb_w1[o * 363 + (k % 3) * 121 + ki * 11 + (k / 3)];
        W[idx] = f2b(v);
    } else if (idx < 722944) {                       // Wt2 [5][256][512]
        int i = idx - 67584;
        int kp = i & 511, o = (i >> 9) & 255, ki = i >> 17;
        float v = 0.f;
        if (kp < 480) v = bb_w2[(o * 96 + (kp % 96)) * 25 + ki * 5 + kp / 96];
        W[idx] = f2b(v);
    } else if (idx < 1607680) {                      // Wt3 [3][384][768]
        int i = idx - 722944;
        int kp = i % 768, o = (i / 768) % 384, ki = i / 294912;
        W[idx] = f2b(bb_w3[(o * 256 + (kp & 255)) * 9 + ki * 3 + (kp >> 8)]);
    } else if (idx < 2934784) {                      // Wt4 [3][384][1152]
        int i = idx - 1607680;
        int kp = i % 1152, o = (i / 1152) % 384, ki = i / 442368;
        W[idx] = f2b(bb_w4[(o * 384 + (kp % 384)) * 9 + ki * 3 + kp / 384]);
    } else if (idx < 3819520) {                      // Wt5 [3][256][1152]
        int i = idx - 2934784;
        int kp = i % 1152, o = (i / 1152) % 256, ki = i / 294912;
        W[idx] = f2b(bb_w5[(o * 384 + (kp % 384)) * 9 + ki * 3 + kp / 384]);
    } else if (idx < 4999168) {                      // Wtrc [3][512][768]
        int i = idx - 3819520;
        int kp = i % 768, o = (i / 768) % 512, ki = i / 393216;
        const float* src = (o < 256) ? wr : wc;
        W[idx] = f2b(src[((o & 255) * 256 + (kp & 255)) * 9 + ki * 3 + (kp >> 8)]);
    } else if (idx < 5130240) {                      // Wh1 [256][256] x2
        int i = idx - 4999168;
        const float* src = (i < 65536) ? ch_w1 : rh_w1;
        W[idx] = f2b(src[i & 65535]);
    } else if (idx < 5195776) {                      // zt [8][16][256] x2
        int i = idx - 5130240;
        const float* src = (i < 32768) ? z_cls : z_reg;
        int j = i & 32767;
        int c = j & 255, k = (j >> 8) & 15, m = j >> 12;
        W[idx] = f2b(src[m * 4096 + c * 16 + k]);
    } else if (idx < 5196800) {                      // biases 1024 f32
        int i = idx - 5195776;
        const float* src = (i < 256) ? br : (i < 512) ? bc : (i < 768) ? chb1 : rhb1;
        biasf[i] = src[i & 255];
    } else {                                         // xb 247107 f32->bf16
        int i = idx - 5196800;
        if (i < 247107) xb[i] = f2b(x[i]);
    }
}

// ---------------- coalesced double-buffered implicit-GEMM (bf16 MFMA) ----------------
// in: NHWC bf16; wt: [ki][Ot][KwCp] bf16 (K-rows padded to BK multiple, zeros in pad)
// Block 64m x 64n, 4 waves (2x2) of 32x32. Staging is row-coalesced:
// thread t loads 8-short chunk (t%CPR) of tile-row (q*RPR + t/CPR), q = 0..BKC-1.
template <int BKC>
__global__ __launch_bounds__(256) void gemm_k(
        const short* __restrict__ in, const short* __restrict__ wt,
        const float* __restrict__ bias, short* __restrict__ out,
        int M, int N, int Wo, int CinW, int Cin,
        int S, int SPR, int aWrap, int bWrap, int KwCp,
        int relu, int msplit, int wsec, int bsec, int nt) {
    constexpr int BK = BKC * 32;
    constexpr int LDW = BK + 8;
    constexpr int CPR = BK / 8;        // 8-short chunks per row
    constexpr int RPR = 256 / CPR;     // rows per round
    __shared__ short sa[2][64 * LDW];
    __shared__ short sb[2][64 * LDW];

    int bid = blockIdx.x;
    int m0 = (bid / nt) * 64, n0 = (bid % nt) * 64;
    int t = threadIdx.x;
    int lane = t & 63;
    int wid = t >> 6, wm = wid >> 1, wn = wid & 1;
    int sec = (m0 >= msplit) ? 1 : 0;
    const short* wts = wt + (size_t)sec * wsec;
    const float* bs = bias + sec * bsec;

    int rql = t / CPR;
    int ch8 = (t % CPR) * 8;

    const short* pA[BKC];
    const short* pB[BKC];
#pragma unroll
    for (int q = 0; q < BKC; ++q) {
        int mr = m0 + q * RPR + rql; if (mr > M - 1) mr = M - 1;
        int oy = mr / Wo, ox = mr - oy * Wo;
        pA[q] = in + (size_t)oy * CinW + (size_t)ox * Cin + ch8;
        int nr = n0 + q * RPR + rql; if (nr > N - 1) nr = N - 1;
        pB[q] = wts + (size_t)nr * KwCp + ch8;
    }
    int swb = rql * LDW + ch8;

    int arow = (wm * 32 + (lane & 15)) * LDW + (lane >> 4) * 8;
    int brow = (wn * 32 + (lane & 15)) * LDW + (lane >> 4) * 8;

    f4 acc[2][2] = {};
    bf8 va[BKC], vb[BKC];
    int srow = 0;

#define LOAD_STEP()                                                           \
    do {                                                                      \
        _Pragma("unroll")                                                     \
        for (int q = 0; q < BKC; ++q) {                                       \
            va[q] = *(const bf8*)pA[q];                                       \
            vb[q] = *(const bf8*)pB[q];                                       \
        }                                                                     \
        if (++srow == SPR) {                                                  \
            srow = 0;                                                         \
            _Pragma("unroll")                                                 \
            for (int q = 0; q < BKC; ++q) { pA[q] += aWrap; pB[q] += bWrap; } \
        } else {                                                              \
            _Pragma("unroll")                                                 \
            for (int q = 0; q < BKC; ++q) { pA[q] += BK; pB[q] += BK; }       \
        }                                                                     \
    } while (0)

    LOAD_STEP();
#pragma unroll
    for (int q = 0; q < BKC; ++q) {
        *(bf8*)&sa[0][swb + q * (RPR * LDW)] = va[q];
        *(bf8*)&sb[0][swb + q * (RPR * LDW)] = vb[q];
    }
    __syncthreads();

    for (int s = 0; s < S; ++s) {
        int cur = s & 1;
        bool pre = (s + 1 < S);
        if (pre) LOAD_STEP();
        const short* A = sa[cur];
        const short* B = sb[cur];
#pragma unroll
        for (int kc = 0; kc < BKC; ++kc) {
            bf8 a0 = *(const bf8*)&A[arow + kc * 32];
            bf8 a1 = *(const bf8*)&A[arow + 16 * LDW + kc * 32];
            bf8 b0 = *(const bf8*)&B[brow + kc * 32];
            bf8 b1 = *(const bf8*)&B[brow + 16 * LDW + kc * 32];
            acc[0][0] = __builtin_amdgcn_mfma_f32_16x16x32_bf16(a0, b0, acc[0][0], 0, 0, 0);
            acc[0][1] = __builtin_amdgcn_mfma_f32_16x16x32_bf16(a0, b1, acc[0][1], 0, 0, 0);
            acc[1][0] = __builtin_amdgcn_mfma_f32_16x16x32_bf16(a1, b0, acc[1][0], 0, 0, 0);
            acc[1][1] = __builtin_amdgcn_mfma_f32_16x16x32_bf16(a1, b1, acc[1][1], 0, 0, 0);
        }
        if (pre) {
            int nb = cur ^ 1;
#pragma unroll
            for (int q = 0; q < BKC; ++q) {
                *(bf8*)&sa[nb][swb + q * (RPR * LDW)] = va[q];
                *(bf8*)&sb[nb][swb + q * (RPR * LDW)] = vb[q];
            }
        }
        __syncthreads();
    }
#undef LOAD_STEP

#pragma unroll
    for (int i = 0; i < 2; ++i) {
#pragma unroll
        for (int j = 0; j < 2; ++j) {
            int gm_base = m0 + wm * 32 + i * 16 + (lane >> 4) * 4;
            int gn = n0 + wn * 32 + j * 16 + (lane & 15);
            if (gn < N) {
                float bv = bs[gn];
#pragma unroll
                for (int r = 0; r < 4; ++r) {
                    int gm = gm_base + r;
                    if (gm < M) {
                        float v = acc[i][j][r] + bv;
                        if (relu) v = fmaxf(v, 0.f);
                        out[(size_t)gm * N + gn] = f2b(v);
                    }
                }
            }
        }
    }
}

// ---------------- maxpool 3x3 s2 + relu, NHWC bf16 ----------------
__global__ void pool_k(const short* __restrict__ in, short* __restrict__ out,
                       int C8, int Win, int Ho) {
    int idx = blockIdx.x * blockDim.x + threadIdx.x;
    int total = Ho * Ho * C8;
    if (idx >= total) return;
    int c8 = idx % C8;
    int p = idx / C8;
    int oy = p / Ho, ox = p % Ho;
    int C = C8 * 8;
    float mx[8];
#pragma unroll
    for (int e = 0; e < 8; ++e) mx[e] = -INFINITY;
#pragma unroll
    for (int ki = 0; ki < 3; ++ki)
#pragma unroll
        for (int kj = 0; kj < 3; ++kj) {
            const bf8 v = *(const bf8*)(in + ((size_t)(oy * 2 + ki) * Win + ox * 2 + kj) * C + c8 * 8);
#pragma unroll
            for (int e = 0; e < 8; ++e) mx[e] = fmaxf(mx[e], b2f((unsigned short)v[e]));
        }
    bf8 o;
#pragma unroll
    for (int e = 0; e < 8; ++e) o[e] = f2b(fmaxf(mx[e], 0.f));
    *(bf8*)(out + (size_t)p * C + c8 * 8) = o;
}

// ---------------- depthwise 4x4 correlation, NHWC, bf16 z (transposed [m][k][c]) ----------------
__global__ void dwcorr_k(const short* __restrict__ in, const short* __restrict__ zt,
                         short* __restrict__ out) {
    int idx = blockIdx.x * blockDim.x + threadIdx.x;
    if (idx >= 8 * 441 * 256) return;
    int c = idx & 255;
    int l = (idx >> 8) % 441;
    int mb = idx / (441 * 256);
    int y = l / 21, x = l % 21;
    const short* ip = in + (size_t)(y * 24 + x) * 512 + c;
    const short* zp = zt + mb * 4096 + c;
    float acc = 0.f;
#pragma unroll
    for (int ki = 0; ki < 4; ++ki)
#pragma unroll
        for (int kj = 0; kj < 4; ++kj)
            acc = fmaf(b2f((unsigned short)ip[(ki * 24 + kj) * 512]),
                       b2f((unsigned short)zp[(ki * 4 + kj) * 256]), acc);
    out[((size_t)mb * 441 + l) * 256 + c] = f2b(acc);
}

// ---------------- head layer-2 ----------------
__global__ void head2_k(const short* __restrict__ hid,
                        const float* __restrict__ chw2, const float* __restrict__ chb2,
                        const float* __restrict__ rhw2, const float* __restrict__ rhb2,
                        float* __restrict__ cls2, float* __restrict__ reg2) {
    int idx = blockIdx.x * blockDim.x + threadIdx.x;
    if (idx >= 35280 + 70560) return;
    const short* h;
    const float* wp;
    float acc;
    float* op;
    if (idx < 35280) {
        int ml = idx / 10, o = idx % 10;
        h = hid + (size_t)ml * 256;
        wp = chw2 + o * 256;
        acc = chb2[o];
        op = cls2 + idx;
    } else {
        int j = idx - 35280;
        int ml = j / 20, o = j % 20;
        h = hid + (size_t)(3584 + ml) * 256;
        wp = rhw2 + o * 256;
        acc = rhb2[o];
        op = reg2 + j;
    }
    for (int c = 0; c < 256; c += 8) {
        bf8 hv = *(const bf8*)(h + c);
#pragma unroll
        for (int e = 0; e < 8; ++e)
            acc = fmaf(b2f((unsigned short)hv[e]), wp[c + e], acc);
    }
    *op = acc;
}

// ---------------- epilogue ----------------
__global__ void epilogue_k(const float* __restrict__ cls2, const float* __restrict__ reg2,
                           const float* __restrict__ a0, const float* __restrict__ a1,
                           const float* __restrict__ a2, const float* __restrict__ a3,
                           float* __restrict__ out) {
    const int Ntot = 8 * 2205;
    int idx = blockIdx.x * blockDim.x + threadIdx.x;
    if (idx >= Ntot) return;
    int m = idx / 2205, j = idx % 2205;
    int a = j / 441, pos = j % 441;
    int ml = m * 441 + pos;
    float c0 = cls2[ml * 10 + a];
    float c1 = cls2[ml * 10 + 5 + a];
    float s1 = 1.f / (1.f + expf(c0 - c1));
    float dl0 = reg2[ml * 20 + a];
    float dl1 = reg2[ml * 20 + 5 + a];
    float dl2 = reg2[ml * 20 + 10 + a];
    float dl3 = reg2[ml * 20 + 15 + a];
    float A2 = a2[idx], A3 = a3[idx];
    out[0 * Ntot + idx] = fmaf(dl0, A2, a0[idx]);
    out[1 * Ntot + idx] = fmaf(dl1, A3, a1[idx]);
    out[2 * Ntot + idx] = expf(dl2) * A2;
    out[3 * Ntot + idx] = expf(dl3) * A3;
    out[4 * Ntot + idx] = s1;
}

extern "C" void kernel_launch(void* const* d_in, const int* in_sizes, int n_in,
                              void* d_out, int out_size, void* d_ws, size_t ws_size,
                              hipStream_t stream) {
    const float* x     = (const float*)d_in[0];
    const float* z_reg = (const float*)d_in[1];
    const float* z_cls = (const float*)d_in[2];
    const float* bb_w1 = (const float*)d_in[3];
    const float* bb_b1 = (const float*)d_in[4];
    const float* bb_w2 = (const float*)d_in[5];
    const float* bb_b2 = (const float*)d_in[6];
    const float* bb_w3 = (const float*)d_in[7];
    const float* bb_b3 = (const float*)d_in[8];
    const float* bb_w4 = (const float*)d_in[9];
    const float* bb_b4 = (const float*)d_in[10];
    const float* bb_w5 = (const float*)d_in[11];
    const float* bb_b5 = (const float*)d_in[12];
    const float* wr    = (const float*)d_in[13];
    const float* br    = (const float*)d_in[14];
    const float* wc    = (const float*)d_in[15];
    const float* bc    = (const float*)d_in[16];
    const float* rh_w1 = (const float*)d_in[17];
    const float* rh_b1 = (const float*)d_in[18];
    const float* rh_w2 = (const float*)d_in[19];
    const float* rh_b2 = (const float*)d_in[20];
    const float* ch_w1 = (const float*)d_in[21];
    const float* ch_b1 = (const float*)d_in[22];
    const float* ch_w2 = (const float*)d_in[23];
    const float* ch_b2 = (const float*)d_in[24];
    const float* anc0  = (const float*)d_in[25];
    const float* anc1  = (const float*)d_in[26];
    const float* anc2  = (const float*)d_in[27];
    const float* anc3  = (const float*)d_in[28];

    short* sws  = (short*)d_ws;
    short* W    = sws;
    float* biasf = (float*)(sws + OBIAS);
    short* act1 = sws + OACT1;              // later: hid
    short* pool1 = sws + OP1;
    short* actB = sws + OACTB;
    short* xb   = actB + XB_OFF;
    short* act2 = actB + ACT2_OFF;
    short* pool2 = actB + POOL2_OFF;
    short* act3 = actB + ACT3_OFF;
    short* act4 = actB + ACT4_OFF;
    short* corr = actB + CORR_OFF;
    short* xf   = sws + OXF;
    short* crcb = sws + OCRC;
    float* cls2 = (float*)(sws + OCRC);     // reuse crc region after dwcorr
    float* reg2 = cls2 + 35280;
    short* hid  = act1;                     // reuse act1 region

    const int BIG = 1 << 30;

    // 1. fused prep (weights, biases, z-transpose, x->bf16)
    wprep_k<<<cdiv(5196800 + 247107, TPB), TPB, 0, stream>>>(
        bb_w1, bb_w2, bb_w3, bb_w4, bb_w5, wr, wc, ch_w1, rh_w1,
        z_cls, z_reg, br, bc, ch_b1, rh_b1, x, W, biasf, xb);

    // 2. conv1: M=19321 N=96, 11 ki-rows of K=64 (33 real)
    gemm_k<2><<<302 * 2, 256, 0, stream>>>(
        xb, W + OW1, bb_b1, act1,
        19321, 96, 139, 1722, 6,
        11, 1, 861, 6144, 64, 0, BIG, 0, 0, 2);
    pool_k<<<cdiv(69 * 69 * 12, TPB), TPB, 0, stream>>>(act1, pool1, 12, 139, 69);

    // 3. conv2: M=4225 N=256, K=5x512(480 real), S=20
    gemm_k<4><<<67 * 4, 256, 0, stream>>>(
        pool1, W + OW2, bb_b2, act2,
        4225, 256, 65, 6624, 96,
        20, 4, 6240, 130688, 512, 0, BIG, 0, 0, 4);
    pool_k<<<cdiv(32 * 32 * 32, TPB), TPB, 0, stream>>>(act2, pool2, 32, 65, 32);

    // 4. conv3: S=18
    gemm_k<4><<<15 * 6, 256, 0, stream>>>(
        pool2, W + OW3, bb_b3, act3,
        900, 384, 30, 8192, 256,
        18, 6, 7552, 294272, 768, 1, BIG, 0, 0, 6);

    // 5. conv4: S=27
    gemm_k<4><<<13 * 6, 256, 0, stream>>>(
        act3, W + OW4, bb_b4, act4,
        784, 384, 28, 11520, 384,
        27, 9, 10496, 441344, 1152, 1, BIG, 0, 0, 6);

    // 6. conv5: S=27 (no relu)
    gemm_k<4><<<11 * 4, 256, 0, stream>>>(
        act4, W + OW5, bb_b5, xf,
        676, 256, 26, 10752, 384,
        27, 9, 9728, 293888, 1152, 0, BIG, 0, 0, 4);

    // 7. conv_reg2|conv_cls2 fused: N=512, S=18
    gemm_k<4><<<9 * 8, 256, 0, stream>>>(
        xf, W + OWRC, biasf, crcb,
        576, 512, 24, 6656, 256,
        18, 6, 6016, 392576, 768, 1, BIG, 0, 0, 8);

    // 8. depthwise correlation (c_x = crc cols 0..255 with z_cls; r_x with z_reg)
    dwcorr_k<<<cdiv(8 * 441 * 256, TPB), TPB, 0, stream>>>(crcb, W + OZT, corr);
    dwcorr_k<<<cdiv(8 * 441 * 256, TPB), TPB, 0, stream>>>(crcb + 256, W + OZT + 32768,
                                                           corr + (size_t)3584 * 256);

    // 9. head layer-1: M=7112 (split 3584), K=256, S=2
    gemm_k<4><<<112 * 4, 256, 0, stream>>>(
        corr, W + OWH1, biasf + 512, hid,
        7112, 256, 7112, 0, 256,
        2, 2, 0, 0, 256, 1, 3584, 65536, 256, 4);

    // 10. head layer-2 + decode
    head2_k<<<cdiv(35280 + 70560, TPB), TPB, 0, stream>>>(hid, ch_w2, ch_b2, rh_w2, rh_b2, cls2, reg2);
    epilogue_k<<<cdiv(8 * 2205, TPB), TPB, 0, stream>>>(cls2, reg2, anc0, anc1, anc2, anc3,
                                                        (float*)d_out);
}